// Round 1
// baseline (350.806 us; speedup 1.0000x reference)
//
#include <hip/hip_runtime.h>
#include <math.h>

// ---------------- problem constants ----------------
#define PATCH   11
#define PP      121          // PATCH*PATCH
#define NPX     35           // (80-11)/2+1 patches per row/col
#define NPATCH  1225         // per image
#define P2      2450         // x-patches + y-patches
#define NC      3
#define NB      2
#define TILE    64
#define NT      39           // ceil(P2/TILE)
#define NTP     ((NT*(NT+1))/2)   // 780 upper-triangular tile pairs
#define C1f     1.0e-4f      // 0.01^2
#define C2f     9.0e-4f      // 0.03^2

// ---------------------------------------------------------------------------
// Kernel 1: patch extraction + per-patch stats.
//   Z[b][c][p][i]   = sqrt(win[p]) * X[i,c,p]     (i contiguous -> coalesced)
//   musq[b][c][i]   = mu^2
//   sig [b][c][i]   = E_w[X^2] - mu^2
// ---------------------------------------------------------------------------
__global__ void extract_kernel(const float* __restrict__ x,
                               const float* __restrict__ y,
                               float* __restrict__ Z,
                               float* __restrict__ musq,
                               float* __restrict__ sig) {
    int i = blockIdx.x * blockDim.x + threadIdx.x;
    int c = blockIdx.y;
    int b = blockIdx.z;
    if (i >= P2) return;

    const float* img = (i < NPATCH) ? x : y;
    int ip = (i < NPATCH) ? i : i - NPATCH;
    int py = ip / NPX, px = ip - py * NPX;
    const float* base = img + ((size_t)(b * NC + c) * 80 + py * 2) * 80 + px * 2;

    // 1D gaussian (matches reference: exp(-d^2/(2*1.5^2)), normalized)
    float g[PATCH];
    float gs = 0.f;
#pragma unroll
    for (int k = 0; k < PATCH; k++) {
        float d = (float)(k - PATCH / 2);
        g[k] = expf(-(d * d) / (2.0f * 1.5f * 1.5f));
        gs += g[k];
    }
    float gn = 1.0f / gs;

    float mu = 0.f, e2 = 0.f;
    float* Zc = Z + (size_t)(b * NC + c) * PP * P2;
#pragma unroll 1
    for (int p = 0; p < PP; p++) {
        int r = p / PATCH, s = p - r * PATCH;
        float w = (g[r] * gn) * (g[s] * gn);
        float v = base[r * 80 + s];
        float X = (v + 1.0f) * 0.5f;
        mu += w * X;
        e2 += w * X * X;
        Zc[(size_t)p * P2 + i] = sqrtf(w) * X;
    }
    float m2 = mu * mu;
    musq[(size_t)(b * NC + c) * P2 + i] = m2;
    sig [(size_t)(b * NC + c) * P2 + i] = e2 - m2;
}

// ---------------------------------------------------------------------------
// Kernel 2: pairwise Gram (per channel) + fused SSIM epilogue + reduction.
// One block = one 64x64 tile of the (2450 x 2450) pair matrix, upper
// triangle only (tj >= ti); off-diagonal tiles counted with weight 2.
// ---------------------------------------------------------------------------
__global__ __launch_bounds__(256) void pair_kernel(const float* __restrict__ Z,
                                                   const float* __restrict__ musq,
                                                   const float* __restrict__ sig,
                                                   double* __restrict__ acc) {
    // decode upper-triangular tile pair from linear index
    int l = blockIdx.x;
    int b = blockIdx.y;
    int ti = 0;
    while (l >= NT - ti) { l -= NT - ti; ti++; }
    int tj = ti + l;

    __shared__ float Zi[PP][TILE];
    __shared__ float Zj[PP][TILE];
    __shared__ double red[4];

    int t = threadIdx.x;
    int i0 = (t & 15) * 4;   // 0..60
    int j0 = (t >> 4) * 4;   // 0..60

    float accg[NC][16];
#pragma unroll
    for (int c = 0; c < NC; c++)
#pragma unroll
        for (int k = 0; k < 16; k++) accg[c][k] = 0.f;

#pragma unroll
    for (int c = 0; c < NC; c++) {
        __syncthreads();   // protect LDS reuse across channels
        const float* Zc = Z + (size_t)(b * NC + c) * PP * P2;
        for (int idx = t; idx < PP * TILE; idx += 256) {
            int p = idx >> 6, ii = idx & 63;
            int gi = ti * TILE + ii;
            int gj = tj * TILE + ii;
            Zi[p][ii] = (gi < P2) ? Zc[(size_t)p * P2 + gi] : 0.f;
            Zj[p][ii] = (gj < P2) ? Zc[(size_t)p * P2 + gj] : 0.f;
        }
        __syncthreads();
#pragma unroll 1
        for (int p = 0; p < PP; p++) {
            float4 av = *(const float4*)&Zi[p][i0];
            float4 bv = *(const float4*)&Zj[p][j0];
            float am[4] = {av.x, av.y, av.z, av.w};
            float bn[4] = {bv.x, bv.y, bv.z, bv.w};
#pragma unroll
            for (int m = 0; m < 4; m++)
#pragma unroll
                for (int n = 0; n < 4; n++)
                    accg[c][m * 4 + n] = fmaf(am[m], bn[n], accg[c][m * 4 + n]);
        }
    }

    // fused SSIM epilogue; accumulate weighted kernel entries in double
    double local = 0.0;
#pragma unroll
    for (int m = 0; m < 4; m++) {
        int gi = ti * TILE + i0 + m;
#pragma unroll
        for (int n = 0; n < 4; n++) {
            int gj = tj * TILE + j0 + n;
            if (gi >= P2 || gj >= P2 || gj < gi) continue;
            float ksum = 0.f;
#pragma unroll
            for (int c = 0; c < NC; c++) {
                float mi = musq[(size_t)(b * NC + c) * P2 + gi];
                float mj = musq[(size_t)(b * NC + c) * P2 + gj];
                float si = sig [(size_t)(b * NC + c) * P2 + gi];
                float sj = sig [(size_t)(b * NC + c) * P2 + gj];
                float G  = accg[c][m * 4 + n];
                float mm  = mi * mj;          // mus_mult
                float sxy = G - mm;           // sigmas_xy
                float num = (2.f * sxy + C2f) * (2.f * mm + C1f);
                float den = (si + sj + C2f) * (mi + mj + C1f);
                ksum += num / den;
            }
            float w   = (gj > gi) ? 2.f : 1.f;
            float sgn = ((gi < NPATCH) == (gj < NPATCH)) ? 1.f : -1.f;
            local += (double)(w * sgn * ksum);
        }
    }

    // wave shuffle reduce (64 lanes) then cross-wave via LDS
#pragma unroll
    for (int off = 32; off > 0; off >>= 1)
        local += __shfl_down(local, off);
    int wid = t >> 6, lane = t & 63;
    if (lane == 0) red[wid] = local;
    __syncthreads();
    if (t == 0)
        atomicAdd(acc, red[0] + red[1] + red[2] + red[3]);
}

// ---------------------------------------------------------------------------
// Kernel 3: final scale:  loss = acc / (B * 3 * 1225^2)
// ---------------------------------------------------------------------------
__global__ void finalize_kernel(const double* __restrict__ acc,
                                float* __restrict__ out) {
    if (threadIdx.x == 0 && blockIdx.x == 0)
        out[0] = (float)(acc[0] * (1.0 / (2.0 * 3.0 * (double)NPATCH * (double)NPATCH)));
}

// ---------------------------------------------------------------------------
extern "C" void kernel_launch(void* const* d_in, const int* in_sizes, int n_in,
                              void* d_out, int out_size, void* d_ws, size_t ws_size,
                              hipStream_t stream) {
    const float* x = (const float*)d_in[0];
    const float* y = (const float*)d_in[1];
    float* out = (float*)d_out;

    // workspace layout: [double acc (16B aligned slot)] [Z] [musq] [sig]
    double* acc = (double*)d_ws;
    float* Z    = (float*)((char*)d_ws + 16);
    size_t z_elems = (size_t)NB * NC * PP * P2;
    float* musq = Z + z_elems;
    float* sig  = musq + (size_t)NB * NC * P2;

    hipMemsetAsync(d_ws, 0, 16, stream);

    dim3 g1((P2 + 255) / 256, NC, NB);
    extract_kernel<<<g1, 256, 0, stream>>>(x, y, Z, musq, sig);

    dim3 g2(NTP, NB);
    pair_kernel<<<g2, 256, 0, stream>>>(Z, musq, sig, acc);

    finalize_kernel<<<1, 64, 0, stream>>>(acc, out);
}

// Round 2
// 139.239 us; speedup vs baseline: 2.5194x; 2.5194x over previous
//
#include <hip/hip_runtime.h>
#include <math.h>

// ---------------- problem constants ----------------
#define PATCH   11
#define PP      121          // PATCH*PATCH
#define NPX     35           // (80-11)/2+1 patches per row/col
#define NPATCH  1225         // per image
#define P2      2450         // x-patches + y-patches
#define NC      3
#define NB      2
#define TILE    64
#define NT      39           // ceil(P2/TILE)
#define NTP     ((NT*(NT+1))/2)   // 780 upper-triangular tile pairs
#define NROW    (NT*TILE)    // 2496 padded rows
#define KP      128          // padded K (PP=121 -> 128)
#define C1f     1.0e-4f      // 0.01^2
#define C2f     9.0e-4f      // 0.03^2

typedef _Float16 f16;
typedef __attribute__((ext_vector_type(8))) _Float16 f16x8;
typedef __attribute__((ext_vector_type(4))) float     f32x4;

// async global->LDS, 16B per lane; LDS dest is wave-uniform base + lane*16
__device__ __forceinline__ void gload16(const void* g, void* l) {
    __builtin_amdgcn_global_load_lds((const __attribute__((address_space(1))) void*)(g),
                                     (__attribute__((address_space(3))) void*)(l),
                                     16, 0, 0);
}

// ---------------------------------------------------------------------------
// Kernel 1: patch extraction -> f16 hi/lo split rows + per-patch stats.
//   Zh/Zl[b][c][row=2496][k=128]  (row-major, k-contiguous; zero padded)
//   musq/sig[b][c][row=2496]
// Also zeroes the fp64 accumulator (ws is re-poisoned before every call).
// ---------------------------------------------------------------------------
__global__ __launch_bounds__(256) void extract_kernel(
        const float* __restrict__ x, const float* __restrict__ y,
        f16* __restrict__ Zh, f16* __restrict__ Zl,
        float* __restrict__ musq, float* __restrict__ sig,
        double* __restrict__ acc) {
    int i = blockIdx.x * blockDim.x + threadIdx.x;
    int c = blockIdx.y, b = blockIdx.z;
    if (i == 0 && c == 0 && b == 0) acc[0] = 0.0;   // pair_kernel runs after us
    if (i >= NROW) return;

    // normalized 1D gaussian (matches _fspecial_gauss_1d in f32)
    float g1[PATCH]; float gs = 0.f;
#pragma unroll
    for (int k = 0; k < PATCH; k++) {
        float d = (float)(k - PATCH / 2);
        g1[k] = expf(-(d * d) / (2.0f * 1.5f * 1.5f));
        gs += g1[k];
    }
    float inv = 1.0f / gs;

    bool valid = (i < P2);
    const float* base = x;  // dummy init
    if (valid) {
        const float* img = (i < NPATCH) ? x : y;
        int ip = (i < NPATCH) ? i : i - NPATCH;
        int py = ip / NPX, px = ip - py * NPX;
        base = img + ((size_t)(b * NC + c) * 80 + py * 2) * 80 + px * 2;
    }

    f16* zh = Zh + ((size_t)(b * NC + c) * NROW + i) * KP;
    f16* zl = Zl + ((size_t)(b * NC + c) * NROW + i) * KP;

    float mu = 0.f, e2 = 0.f;
#pragma unroll 1
    for (int p0 = 0; p0 < KP; p0 += 8) {
        f16x8 hv, lv;
#pragma unroll
        for (int q = 0; q < 8; q++) {
            int p = p0 + q;
            float zval = 0.f;
            if (valid && p < PP) {
                int r = p / PATCH, s = p - r * PATCH;
                float w = (g1[r] * inv) * (g1[s] * inv);
                float X = (base[r * 80 + s] + 1.0f) * 0.5f;
                mu = fmaf(w, X, mu);
                e2 = fmaf(w * X, X, e2);
                zval = sqrtf(w) * X;
            }
            f16 h = (f16)zval;
            f16 lo = (f16)(zval - (float)h);
            hv[q] = h; lv[q] = lo;
        }
        *(f16x8*)(zh + p0) = hv;
        *(f16x8*)(zl + p0) = lv;
    }
    float m2 = mu * mu;
    musq[(size_t)(b * NC + c) * NROW + i] = m2;     // 0 for pad rows
    sig [(size_t)(b * NC + c) * NROW + i] = e2 - m2;
}

// ---------------------------------------------------------------------------
// Kernel 2: pairwise Gram via MFMA f16 hi/lo split + fused SSIM + reduction.
// Block = one 64x64 upper-tri tile pair; 4 waves, each a 32x32 quadrant
// (2x2 fragments of mfma_f32_16x16x32_f16). 3 passes: ZhZh^T+ZhZl^T+ZlZh^T.
// LDS: 4 arrays x [64 rows][256 B], XOR-swizzled (byte ^= (row&7)<<4) to
// break the 256B-stride bank conflict; staged with pre-swizzled global src.
// ---------------------------------------------------------------------------
__device__ __forceinline__ f16x8 frag(const f16* arr, int r, int kb) {
    int off = r * 256 + (kb ^ ((r & 7) << 4));
    return *(const f16x8*)((const char*)arr + off);
}

__global__ __launch_bounds__(256) void pair_kernel(
        const f16* __restrict__ Zh, const f16* __restrict__ Zl,
        const float* __restrict__ musq, const float* __restrict__ sig,
        double* __restrict__ acc) {
    __shared__ __align__(16) f16 lds[4 * TILE * KP];   // 64 KiB exactly

    int t = threadIdx.x;
    int lane = t & 63, w = t >> 6;
    int b = blockIdx.y;

    // decode upper-triangular tile pair
    int l = blockIdx.x, ti = 0;
    while (l >= NT - ti) { l -= NT - ti; ti++; }
    int tj = ti + l;

    f16* A_h = lds;                 // i-side hi
    f16* A_l = lds + 8192;          // i-side lo
    f16* B_h = lds + 16384;         // j-side hi
    f16* B_l = lds + 24576;         // j-side lo

    int wr = w >> 1, wc = w & 1;    // wave quadrant
    int rA0 = wr * 32 + (lane & 15);
    int rB0 = wc * 32 + (lane & 15);
    int kb0 = (lane >> 4) * 16;

    // precompute staging offsets (swizzled source): unit U=(w*4+q)*64+lane
    int soff[4];
#pragma unroll
    for (int q = 0; q < 4; q++) {
        int U = (w * 4 + q) * 64 + lane;
        int r = U >> 4, u = U & 15;
        soff[q] = r * 256 + (u ^ (r & 7)) * 16;   // bytes within 16KB tile
    }

    double local = 0.0;

    for (int c = 0; c < NC; c++) {
        __syncthreads();    // previous channel's LDS reads complete
        const char* gAh = (const char*)(Zh + ((size_t)(b * NC + c) * NROW + ti * TILE) * KP);
        const char* gAl = (const char*)(Zl + ((size_t)(b * NC + c) * NROW + ti * TILE) * KP);
        const char* gBh = (const char*)(Zh + ((size_t)(b * NC + c) * NROW + tj * TILE) * KP);
        const char* gBl = (const char*)(Zl + ((size_t)(b * NC + c) * NROW + tj * TILE) * KP);
#pragma unroll
        for (int q = 0; q < 4; q++) {
            int ldo = (w * 4 + q) * 512;          // halfs: wave-uniform base
            gload16(gAh + soff[q], A_h + ldo);
            gload16(gAl + soff[q], A_l + ldo);
            gload16(gBh + soff[q], B_h + ldo);
            gload16(gBl + soff[q], B_l + ldo);
        }
        __syncthreads();    // drains vmcnt before barrier (compiler-emitted)

        f32x4 acc2[2][2] = {};
#pragma unroll
        for (int ks = 0; ks < 4; ks++) {
            int kb = ks * 64 + kb0;
            f16x8 ah0 = frag(A_h, rA0,      kb);
            f16x8 ah1 = frag(A_h, rA0 + 16, kb);
            f16x8 al0 = frag(A_l, rA0,      kb);
            f16x8 al1 = frag(A_l, rA0 + 16, kb);
            f16x8 bh0 = frag(B_h, rB0,      kb);
            f16x8 bh1 = frag(B_h, rB0 + 16, kb);
            f16x8 bl0 = frag(B_l, rB0,      kb);
            f16x8 bl1 = frag(B_l, rB0 + 16, kb);
            // pass hh
            acc2[0][0] = __builtin_amdgcn_mfma_f32_16x16x32_f16(ah0, bh0, acc2[0][0], 0, 0, 0);
            acc2[0][1] = __builtin_amdgcn_mfma_f32_16x16x32_f16(ah0, bh1, acc2[0][1], 0, 0, 0);
            acc2[1][0] = __builtin_amdgcn_mfma_f32_16x16x32_f16(ah1, bh0, acc2[1][0], 0, 0, 0);
            acc2[1][1] = __builtin_amdgcn_mfma_f32_16x16x32_f16(ah1, bh1, acc2[1][1], 0, 0, 0);
            // pass hl (A_h x B_l)
            acc2[0][0] = __builtin_amdgcn_mfma_f32_16x16x32_f16(ah0, bl0, acc2[0][0], 0, 0, 0);
            acc2[0][1] = __builtin_amdgcn_mfma_f32_16x16x32_f16(ah0, bl1, acc2[0][1], 0, 0, 0);
            acc2[1][0] = __builtin_amdgcn_mfma_f32_16x16x32_f16(ah1, bl0, acc2[1][0], 0, 0, 0);
            acc2[1][1] = __builtin_amdgcn_mfma_f32_16x16x32_f16(ah1, bl1, acc2[1][1], 0, 0, 0);
            // pass lh (A_l x B_h)
            acc2[0][0] = __builtin_amdgcn_mfma_f32_16x16x32_f16(al0, bh0, acc2[0][0], 0, 0, 0);
            acc2[0][1] = __builtin_amdgcn_mfma_f32_16x16x32_f16(al0, bh1, acc2[0][1], 0, 0, 0);
            acc2[1][0] = __builtin_amdgcn_mfma_f32_16x16x32_f16(al1, bh0, acc2[1][0], 0, 0, 0);
            acc2[1][1] = __builtin_amdgcn_mfma_f32_16x16x32_f16(al1, bh1, acc2[1][1], 0, 0, 0);
        }

        // fused SSIM epilogue for this channel
        const float* msq = musq + (size_t)(b * NC + c) * NROW;
        const float* sg  = sig  + (size_t)(b * NC + c) * NROW;
        int row0 = ti * TILE + wr * 32;
        int col0 = tj * TILE + wc * 32;
        float mjv[2], sjv[2]; int gjv[2];
#pragma unroll
        for (int fn = 0; fn < 2; fn++) {
            int gj = col0 + fn * 16 + (lane & 15);
            gjv[fn] = gj; mjv[fn] = msq[gj]; sjv[fn] = sg[gj];
        }
#pragma unroll
        for (int fm = 0; fm < 2; fm++) {
#pragma unroll
            for (int rg = 0; rg < 4; rg++) {
                int gi = row0 + fm * 16 + (lane >> 4) * 4 + rg;
                float mi = msq[gi], si = sg[gi];
                bool xi = gi < NPATCH;
#pragma unroll
                for (int fn = 0; fn < 2; fn++) {
                    int gj = gjv[fn];
                    float G   = acc2[fm][fn][rg];
                    float mm  = mi * mjv[fn];
                    float sxy = G - mm;
                    float num = (2.f * mm + C1f) * (2.f * sxy + C2f);
                    float den = (mi + mjv[fn] + C1f) * (si + sjv[fn] + C2f);
                    float kv  = num * __builtin_amdgcn_rcpf(den);
                    float wgt;
                    if (ti == tj) wgt = (gj > gi) ? 2.f : ((gj == gi) ? 1.f : 0.f);
                    else          wgt = 2.f;
                    if (gi >= P2 || gj >= P2) wgt = 0.f;
                    float sgn = (xi == (gj < NPATCH)) ? 1.f : -1.f;
                    local += (double)(wgt * sgn * kv);
                }
            }
        }
    }

    // block reduction: wave shuffle, then cross-wave via (reused) LDS
    __syncthreads();   // all LDS frag reads done; safe to reuse lds
#pragma unroll
    for (int off = 32; off > 0; off >>= 1)
        local += __shfl_down(local, off);
    double* red = (double*)lds;
    if (lane == 0) red[w] = local;
    __syncthreads();
    if (t == 0)
        atomicAdd(acc, red[0] + red[1] + red[2] + red[3]);
}

// ---------------------------------------------------------------------------
// Kernel 3: final scale:  loss = acc / (B * 3 * 1225^2)
// ---------------------------------------------------------------------------
__global__ void finalize_kernel(const double* __restrict__ acc,
                                float* __restrict__ out) {
    if (threadIdx.x == 0 && blockIdx.x == 0)
        out[0] = (float)(acc[0] * (1.0 / (2.0 * 3.0 * (double)NPATCH * (double)NPATCH)));
}

// ---------------------------------------------------------------------------
extern "C" void kernel_launch(void* const* d_in, const int* in_sizes, int n_in,
                              void* d_out, int out_size, void* d_ws, size_t ws_size,
                              hipStream_t stream) {
    const float* x = (const float*)d_in[0];
    const float* y = (const float*)d_in[1];
    float* out = (float*)d_out;

    // workspace layout (16B aligned): [acc][Zh][Zl][musq][sig]  ~7.8 MB
    double* acc = (double*)d_ws;
    f16* Zh = (f16*)((char*)d_ws + 16);
    size_t zcnt = (size_t)NB * NC * NROW * KP;        // 1,916,928 halfs
    f16* Zl = Zh + zcnt;
    float* musq = (float*)(Zl + zcnt);
    float* sig  = musq + (size_t)NB * NC * NROW;

    dim3 g1((NROW + 255) / 256, NC, NB);
    extract_kernel<<<g1, 256, 0, stream>>>(x, y, Zh, Zl, musq, sig, acc);

    dim3 g2(NTP, NB);
    pair_kernel<<<g2, 256, 0, stream>>>(Zh, Zl, musq, sig, acc);

    finalize_kernel<<<1, 64, 0, stream>>>(acc, out);
}

// Round 3
// 103.497 us; speedup vs baseline: 3.3895x; 1.3454x over previous
//
#include <hip/hip_runtime.h>
#include <math.h>

// ---------------- problem constants ----------------
#define PATCH   11
#define PP      121          // PATCH*PATCH
#define NPX     35           // (80-11)/2+1 patches per row/col
#define NPATCH  1225         // per image
#define P2      2450         // x-patches + y-patches
#define NC      3
#define NB      2
#define TILE    64
#define NT      39           // ceil(P2/TILE)
#define NTP     ((NT*(NT+1))/2)   // 780 upper-triangular tile pairs
#define NROW    (NT*TILE)    // 2496 padded rows
#define KP      128          // padded K (PP=121 -> 128)
#define C1f     1.0e-4f     // 0.01^2
#define C2f     9.0e-4f     // 0.03^2

typedef _Float16 f16;
typedef __attribute__((ext_vector_type(8)))  _Float16 f16x8;
typedef __attribute__((ext_vector_type(16))) float    f32x16;

// async global->LDS, 16B per lane; LDS dest is wave-uniform base + lane*16
__device__ __forceinline__ void gload16(const void* g, void* l) {
    __builtin_amdgcn_global_load_lds((const __attribute__((address_space(1))) void*)(g),
                                     (__attribute__((address_space(3))) void*)(l),
                                     16, 0, 0);
}

// ---------------------------------------------------------------------------
// Kernel 1: patch extraction, one WAVE per output row (2 pixels per lane).
//   Zh/Zl[b][c][row=2496][k=128]  (row-major, k-contiguous; zero padded)
//   musq/sig[b][c][row=2496]
// ---------------------------------------------------------------------------
__global__ __launch_bounds__(256) void extract_kernel(
        const float* __restrict__ x, const float* __restrict__ y,
        f16* __restrict__ Zh, f16* __restrict__ Zl,
        float* __restrict__ musq, float* __restrict__ sig,
        double* __restrict__ acc) {
    int w = threadIdx.x >> 6, lane = threadIdx.x & 63;
    int i = blockIdx.x * 4 + w;
    int c = blockIdx.y, b = blockIdx.z;
    if (threadIdx.x == 0 && blockIdx.x == 0 && c == 0 && b == 0) acc[0] = 0.0;
    if (i >= NROW) return;

    size_t rowbase = ((size_t)(b * NC + c) * NROW + i) * (size_t)KP;
    f16* zh = Zh + rowbase;
    f16* zl = Zl + rowbase;
    size_t sidx = (size_t)(b * NC + c) * NROW + i;

    if (i >= P2) {                      // pad rows: all zeros
        ((unsigned int*)zh)[lane] = 0u;
        ((unsigned int*)zl)[lane] = 0u;
        if (lane == 0) { musq[sidx] = 0.f; sig[sidx] = 0.f; }
        return;
    }

    // normalized 1D gaussian (matches _fspecial_gauss_1d in f32)
    float g1[PATCH]; float gs = 0.f;
#pragma unroll
    for (int k = 0; k < PATCH; k++) {
        float d = (float)(k - PATCH / 2);
        g1[k] = expf(-(d * d) / (2.0f * 1.5f * 1.5f));
        gs += g1[k];
    }
    float inv = 1.0f / gs;
    float inv2 = inv * inv;

    const float* img = (i < NPATCH) ? x : y;
    int ip = (i < NPATCH) ? i : i - NPATCH;
    int py = ip / NPX, px = ip - py * NPX;
    const float* base = img + ((size_t)(b * NC + c) * 80 + py * 2) * 80 + px * 2;

    float mu = 0.f, e2 = 0.f;
    f16 hv[2], lv[2];
#pragma unroll
    for (int q = 0; q < 2; q++) {
        int p = lane + q * 64;
        float z = 0.f;
        if (p < PP) {
            int r = p / PATCH, s = p - (p / PATCH) * PATCH;
            float wgt = g1[r] * g1[s] * inv2;
            float X = (base[r * 80 + s] + 1.0f) * 0.5f;
            mu = fmaf(wgt, X, mu);
            e2 = fmaf(wgt * X, X, e2);
            z = sqrtf(wgt) * X;
        }
        hv[q] = (f16)z;
        lv[q] = (f16)(z - (float)hv[q]);
    }
    zh[lane]      = hv[0];
    zh[lane + 64] = hv[1];
    zl[lane]      = lv[0];
    zl[lane + 64] = lv[1];

#pragma unroll
    for (int off = 32; off > 0; off >>= 1) {
        mu += __shfl_down(mu, off);
        e2 += __shfl_down(e2, off);
    }
    if (lane == 0) {
        float m2 = mu * mu;
        musq[sidx] = m2;
        sig [sidx] = e2 - m2;
    }
}

// ---------------------------------------------------------------------------
// Kernel 2: pairwise Gram via mfma_f32_32x32x16_f16 hi/lo split + fused SSIM.
// Block = one 64x64 upper-tri tile pair; 4 waves, each one 32x32 quadrant,
// single f32x16 accumulator; 3 logical passes hh+hl+lh folded per K-step.
// LDS: 4 arrays x [64 rows][256 B], XOR swizzle byte ^= (row&15)<<4
// (uniform bank spread for the 32-rows-per-column read); staged via
// global_load_lds with pre-swizzled global source.
// ---------------------------------------------------------------------------
__device__ __forceinline__ f16x8 frag(const f16* arr, int r, int kb) {
    int off = r * 256 + (kb ^ ((r & 15) << 4));
    return *(const f16x8*)((const char*)arr + off);
}

__global__ __launch_bounds__(256) void pair_kernel(
        const f16* __restrict__ Zh, const f16* __restrict__ Zl,
        const float* __restrict__ musq, const float* __restrict__ sig,
        double* __restrict__ acc) {
    __shared__ __align__(16) f16 lds[4 * TILE * KP];   // 64 KiB exactly

    int t = threadIdx.x;
    int lane = t & 63, w = t >> 6;
    int b = blockIdx.y;

    // decode upper-triangular tile pair
    int l = blockIdx.x, ti = 0;
    while (l >= NT - ti) { l -= NT - ti; ti++; }
    int tj = ti + l;

    f16* A_h = lds;                 // i-side hi
    f16* A_l = lds + 8192;          // i-side lo
    f16* B_h = lds + 16384;         // j-side hi
    f16* B_l = lds + 24576;         // j-side lo

    int wr = w >> 1, wc = w & 1;    // wave quadrant (32x32)
    int rA = wr * 32 + (lane & 31);
    int rB = wc * 32 + (lane & 31);
    int kb0 = (lane >> 5) * 16;     // byte offset of this lane's 8-half group

    // staging offsets (pre-swizzled source): unit U=(w*4+q)*64+lane, 16B units
    int soff[4];
#pragma unroll
    for (int q = 0; q < 4; q++) {
        int U = (w * 4 + q) * 64 + lane;
        int r = U >> 4, u = U & 15;
        soff[q] = r * 256 + (u ^ (r & 15)) * 16;   // bytes within 16KB tile
    }

    double local = 0.0;

    for (int c = 0; c < NC; c++) {
        __syncthreads();    // previous channel's LDS reads complete
        const char* gAh = (const char*)(Zh + ((size_t)(b * NC + c) * NROW + ti * TILE) * KP);
        const char* gAl = (const char*)(Zl + ((size_t)(b * NC + c) * NROW + ti * TILE) * KP);
        const char* gBh = (const char*)(Zh + ((size_t)(b * NC + c) * NROW + tj * TILE) * KP);
        const char* gBl = (const char*)(Zl + ((size_t)(b * NC + c) * NROW + tj * TILE) * KP);
#pragma unroll
        for (int q = 0; q < 4; q++) {
            int ldo = (w * 4 + q) * 512;          // halfs: wave-uniform base
            gload16(gAh + soff[q], A_h + ldo);
            gload16(gAl + soff[q], A_l + ldo);
            gload16(gBh + soff[q], B_h + ldo);
            gload16(gBl + soff[q], B_l + ldo);
        }
        __syncthreads();    // compiler drains vmcnt before barrier

        f32x16 acc2 = {};
#pragma unroll
        for (int ks = 0; ks < 8; ks++) {
            int kb = ks * 32 + kb0;
            f16x8 ah = frag(A_h, rA, kb);
            f16x8 bh = frag(B_h, rB, kb);
            f16x8 al = frag(A_l, rA, kb);
            f16x8 bl = frag(B_l, rB, kb);
            acc2 = __builtin_amdgcn_mfma_f32_32x32x16_f16(ah, bh, acc2, 0, 0, 0);
            acc2 = __builtin_amdgcn_mfma_f32_32x32x16_f16(ah, bl, acc2, 0, 0, 0);
            acc2 = __builtin_amdgcn_mfma_f32_32x32x16_f16(al, bh, acc2, 0, 0, 0);
        }

        // fused SSIM epilogue for this channel
        const float* msq = musq + (size_t)(b * NC + c) * NROW;
        const float* sg  = sig  + (size_t)(b * NC + c) * NROW;
        int row0 = ti * TILE + wr * 32;
        int col0 = tj * TILE + wc * 32;
        int gj = col0 + (lane & 31);
        float mj = msq[gj], sj = sg[gj];
        bool yj = gj < NPATCH;
#pragma unroll
        for (int reg = 0; reg < 16; reg++) {
            int gi = row0 + (reg & 3) + 8 * (reg >> 2) + 4 * (lane >> 5);
            float mi = msq[gi], si = sg[gi];
            float G   = acc2[reg];
            float mm  = mi * mj;
            float sxy = G - mm;
            float num = (2.f * mm + C1f) * (2.f * sxy + C2f);
            float den = (mi + mj + C1f) * (si + sj + C2f);
            float kv  = num * __builtin_amdgcn_rcpf(den);
            float wgt;
            if (ti == tj) wgt = (gj > gi) ? 2.f : ((gj == gi) ? 1.f : 0.f);
            else          wgt = 2.f;
            if (gi >= P2 || gj >= P2) wgt = 0.f;
            float sgn = ((gi < NPATCH) == yj) ? 1.f : -1.f;
            local += (double)(wgt * sgn * kv);
        }
    }

    // block reduction: wave shuffle, then cross-wave via (reused) LDS
    __syncthreads();   // all LDS frag reads done; safe to reuse lds
#pragma unroll
    for (int off = 32; off > 0; off >>= 1)
        local += __shfl_down(local, off);
    double* red = (double*)lds;
    if (lane == 0) red[w] = local;
    __syncthreads();
    if (t == 0)
        atomicAdd(acc, red[0] + red[1] + red[2] + red[3]);
}

// ---------------------------------------------------------------------------
// Kernel 3: final scale:  loss = acc / (B * 3 * 1225^2)
// ---------------------------------------------------------------------------
__global__ void finalize_kernel(const double* __restrict__ acc,
                                float* __restrict__ out) {
    if (threadIdx.x == 0 && blockIdx.x == 0)
        out[0] = (float)(acc[0] * (1.0 / (2.0 * 3.0 * (double)NPATCH * (double)NPATCH)));
}

// ---------------------------------------------------------------------------
extern "C" void kernel_launch(void* const* d_in, const int* in_sizes, int n_in,
                              void* d_out, int out_size, void* d_ws, size_t ws_size,
                              hipStream_t stream) {
    const float* x = (const float*)d_in[0];
    const float* y = (const float*)d_in[1];
    float* out = (float*)d_out;

    // workspace layout (16B aligned): [acc][Zh][Zl][musq][sig]  ~7.8 MB
    double* acc = (double*)d_ws;
    f16* Zh = (f16*)((char*)d_ws + 16);
    size_t zcnt = (size_t)NB * NC * NROW * KP;        // 1,916,928 halfs
    f16* Zl = Zh + zcnt;
    float* musq = (float*)(Zl + zcnt);
    float* sig  = musq + (size_t)NB * NC * NROW;

    dim3 g1((NROW + 3) / 4, NC, NB);
    extract_kernel<<<g1, 256, 0, stream>>>(x, y, Zh, Zl, musq, sig, acc);

    dim3 g2(NTP, NB);
    pair_kernel<<<g2, 256, 0, stream>>>(Zh, Zl, musq, sig, acc);

    finalize_kernel<<<1, 64, 0, stream>>>(acc, out);
}